// Round 3
// baseline (2430.226 us; speedup 1.0000x reference)
//
#include <hip/hip_runtime.h>
#include <hip/hip_bf16.h>
#include <math.h>

#define TPTS 96
#define CTOT 128
#define LDP 134   // LDS row pitch u16: <=2-way banks (verified R4: conflicts ~0)
#define WP  134   // producer wode/z LDS pitch (same bank analysis as LDP)

typedef __bf16 bf16x8_t __attribute__((ext_vector_type(8)));
typedef float f32x4_t __attribute__((ext_vector_type(4)));
typedef unsigned short us8_t __attribute__((ext_vector_type(8)));

__device__ __forceinline__ unsigned short f2b(float f) {
    union { float f; unsigned int i; } v; v.f = f;
    unsigned int r = v.i + 0x7fffu + ((v.i >> 16) & 1u);
    return (unsigned short)(r >> 16);
}
// HW packed bf16 convert (RNE, matches f2b for finite inputs).
__device__ __forceinline__ unsigned int packbf2(float a, float b) {
    unsigned int r;
    asm("v_cvt_pk_bf16_f32 %0, %1, %2" : "=v"(r) : "v"(a), "v"(b));
    return r;
}
__device__ __forceinline__ uint2 pack4(float v0, float v1, float v2, float v3) {
    uint2 w; w.x = packbf2(v0, v1); w.y = packbf2(v2, v3); return w;
}
// unpack bf16 pair -> f32 (1 VALU op each)
__device__ __forceinline__ float upk_lo(unsigned int w) {
    return __builtin_bit_cast(float, w << 16);
}
__device__ __forceinline__ float upk_hi(unsigned int w) {
    return __builtin_bit_cast(float, w & 0xffff0000u);
}
__device__ __forceinline__ f32x4_t mfma16(bf16x8_t a, bf16x8_t b, f32x4_t c) {
    return __builtin_amdgcn_mfma_f32_16x16x32_bf16(a, b, c, 0, 0, 0);
}
__device__ __forceinline__ bf16x8_t ldfrag(const unsigned short* p) {
    us8_t v = *(const us8_t*)p;
    return __builtin_bit_cast(bf16x8_t, v);
}
// Cross-XCD coherent fragment load: relaxed agent atomics -> plain
// global_load_dwordx2 sc0/sc1 (bypass stale L1/L2, served from LLC).
__device__ __forceinline__ bf16x8_t ldfragG(const unsigned short* p) {
    union { unsigned long long q[2]; us8_t v; } u;
    u.q[0] = __hip_atomic_load((const unsigned long long*)p,
                               __ATOMIC_RELAXED, __HIP_MEMORY_SCOPE_AGENT);
    u.q[1] = __hip_atomic_load((const unsigned long long*)(p + 4),
                               __ATOMIC_RELAXED, __HIP_MEMORY_SCOPE_AGENT);
    return __builtin_bit_cast(bf16x8_t, u.v);
}
// Cross-XCD coherent 8B store: write-through to LLC (chip coherence point).
__device__ __forceinline__ void stg8(unsigned short* p, uint2 pk) {
    unsigned long long q = ((unsigned long long)pk.y << 32) | (unsigned long long)pk.x;
    __hip_atomic_store((unsigned long long*)p, q,
                       __ATOMIC_RELAXED, __HIP_MEMORY_SCOPE_AGENT);
}
__device__ __forceinline__ bf16x8_t ldfragW(const float* p) {
    float4 a = *(const float4*)p;
    float4 b = *(const float4*)(p + 4);
    bf16x8_t r;
    r[0] = __builtin_bit_cast(__bf16, f2b(a.x)); r[1] = __builtin_bit_cast(__bf16, f2b(a.y));
    r[2] = __builtin_bit_cast(__bf16, f2b(a.z)); r[3] = __builtin_bit_cast(__bf16, f2b(a.w));
    r[4] = __builtin_bit_cast(__bf16, f2b(b.x)); r[5] = __builtin_bit_cast(__bf16, f2b(b.y));
    r[6] = __builtin_bit_cast(__bf16, f2b(b.z)); r[7] = __builtin_bit_cast(__bf16, f2b(b.w));
    return r;
}
__device__ __forceinline__ float tanh2(float x) {   // finite inputs only
    float e = __expf(x + x);
    return 1.f - __fdividef(2.f, e + 1.f);
}
// tanh(a+b/ (2log2e)) with pre-scaled bias bl = b*2*log2e; 5 VALU ops total.
#define TWO_LOG2E 2.8853900817779268f
__device__ __forceinline__ float tanhfast(float acc, float bl) {
    float e = __builtin_amdgcn_exp2f(fmaf(acc, TWO_LOG2E, bl));  // exp(2(acc+bo))
    float r = __builtin_amdgcn_rcpf(e + 1.f);
    return fmaf(-2.f, r, 1.f);
}
__device__ __forceinline__ float sigm(float x) {
    return __fdividef(1.f, 1.f + __expf(-x));
}

// Raw barrier: LDS-drain only (keeps global stores draining off-path).
#define LGKM_BAR() do {                                         \
        asm volatile("s_waitcnt lgkmcnt(0)" ::: "memory");      \
        __builtin_amdgcn_s_barrier();                           \
    } while (0)

__device__ __forceinline__ void waitflag(unsigned int* f, unsigned int want) {
    if (threadIdx.x == 0) {
        int guard = 0;
        while (__hip_atomic_load(f, __ATOMIC_RELAXED, __HIP_MEMORY_SCOPE_AGENT) != want) {
            __builtin_amdgcn_s_sleep(1);
            if (++guard > (1 << 22)) break;   // hang-proof: degrade, don't wedge
        }
    }
    __syncthreads();
}

// R7: 192 blocks x 512 thr, role = blockIdx>>6.
// role 0: SINGLE-WAVE barrier-free ODE producer. One wave owns the whole
//   16-row x 128-feat slice state in registers (32 f32/lane); Wode lives in
//   LDS (bf16); per-stage z handoff is a same-wave LDS round trip (lgkmcnt
//   only, NO s_barrier). k1..k5 stored as packed bf16 (z-inputs are bf16
//   quantized anyway); y trajectory accumulates only fresh f32 k's.
// role 1/2: GRU0 / GRU1+head, h-part MFMAs hoisted before the flag poll.
__global__ void __launch_bounds__(512, 1)
ode_forecaster(const float* __restrict__ yl,
               const float* __restrict__ yh,
               const float* __restrict__ Wode,
               const float* __restrict__ bode,
               const float* __restrict__ Wih0,
               const float* __restrict__ Whh0,
               const float* __restrict__ bih0,
               const float* __restrict__ bhh0,
               const float* __restrict__ Wih1,
               const float* __restrict__ Whh1,
               const float* __restrict__ bih1,
               const float* __restrict__ bhh1,
               const float* __restrict__ W1v,
               const float* __restrict__ b1v,
               const float* __restrict__ W2v,
               const float* __restrict__ b2v,
               float* __restrict__ outp,
               char* __restrict__ wsb)
{
    const int role = blockIdx.x >> 6;
    const int c    = blockIdx.x & 63;
    const int tid  = threadIdx.x, lane = tid & 63, wv = tid >> 6;
    const int l15  = lane & 15, quad = lane >> 4;
    const int fbase = wv * 16 + quad * 4;
    const int rbase = c * 16;

    __shared__ __align__(16) unsigned short zbuf[2][16][LDP];
    __shared__ __align__(16) unsigned short hidbuf[16][72];
    __shared__ __align__(16) unsigned short wodeb[128][WP];   // producer only
    __shared__ __align__(16) unsigned short zb[16][WP];       // producer only
    __shared__ __align__(16) float bolb[128];                 // producer only

    unsigned short* yTraj  = (unsigned short*)(wsb);
    unsigned short* h1Traj = (unsigned short*)(wsb + 0x2000000);
    unsigned int*   yflag  = (unsigned int*)(wsb + 0x4000000);
    unsigned int*   h1flag = (unsigned int*)(wsb + 0x4010000);
#define YMAGIC(t)  (0x5E000000u + (unsigned)(t))
#define H1MAGIC(t) (0x6E000000u + (unsigned)(t))

    if (role == 0) {
        // ---- stage Wode f32 -> LDS bf16 [128][WP] (all 8 waves) ----
        {
            int r = tid >> 2, c0 = (tid & 3) * 32;
            const float* wrow = Wode + r * CTOT + c0;
#pragma unroll
            for (int u = 0; u < 32; u += 8) {
                float4 a = *(const float4*)(wrow + u);
                float4 b = *(const float4*)(wrow + u + 4);
                *(uint2*)&wodeb[r][c0 + u]     = pack4(a.x, a.y, a.z, a.w);
                *(uint2*)&wodeb[r][c0 + u + 4] = pack4(b.x, b.y, b.z, b.w);
            }
            if (tid < 128) bolb[tid] = bode[tid] * TWO_LOG2E;
        }

        // ---- wave 0 preps its slice state; others just hit the barrier ----
        const int row = rbase + l15;
        float y[8][4], yn[8][4];
        if (wv == 0) {
#pragma unroll
            for (int j = 0; j < 8; ++j) {
#pragma unroll
                for (int i = 0; i < 4; ++i) {
                    int f = j * 16 + quad * 4 + i;
                    y[j][i] = (f < 32) ? yl[row * 32 + f] : yh[row * 96 + (f - 32)];
                }
                uint2 pk = pack4(y[j][0], y[j][1], y[j][2], y[j][3]);
                *(uint2*)&zb[l15][j * 16 + quad * 4] = pk;
                stg8(yTraj + ((size_t)row) * CTOT + j * 16 + quad * 4, pk);
            }
        }
        __syncthreads();
        if (wv != 0) return;

        asm volatile("s_waitcnt vmcnt(0)" ::: "memory");
        if (lane == 0)
            __hip_atomic_store(&yflag[c * 128 + 0], YMAGIC(0),
                               __ATOMIC_RELAXED, __HIP_MEMORY_SCOPE_AGENT);

        // dt-folded Dormand-Prince coefficients
        const float dt = 1.0f / 95.0f;
        const float d10 = dt * 0.2f;
        const float d20 = dt * (3.f/40.f),  d21 = dt * (9.f/40.f);
        const float d30 = dt * (44.f/45.f), d31 = dt * (-56.f/15.f), d32 = dt * (32.f/9.f);
        const float d40 = dt * (19372.f/6561.f), d41 = dt * (-25360.f/2187.f),
                    d42 = dt * (64448.f/6561.f), d43 = dt * (-212.f/729.f);
        const float d50 = dt * (9017.f/3168.f), d51 = dt * (-355.f/33.f),
                    d52 = dt * (46732.f/5247.f), d53 = dt * (49.f/176.f),
                    d54 = dt * (-5103.f/18656.f);
        const float e0 = dt * (35.f/384.f), e2 = dt * (500.f/1113.f), e3 = dt * (125.f/192.f),
                    e4 = dt * (-2187.f/6784.f), e5 = dt * (11.f/84.f);

        unsigned int kp[5][8][2];   // k1..k5 packed bf16 pairs

#pragma unroll 1
        for (int t = 0; t < 95; ++t) {
#pragma unroll
            for (int s = 0; s < 6; ++s) {
                // current z fragments (written by previous stage; same wave,
                // compiler inserts the lgkmcnt RAW wait -- no barrier needed)
                bf16x8_t zf[4];
#pragma unroll
                for (int kt = 0; kt < 4; ++kt)
                    zf[kt] = ldfrag(&zb[l15][kt * 32 + quad * 8]);
                // pre-scaled bias (broadcast reads, conflict-free)
                float bl[8][4];
#pragma unroll
                for (int j = 0; j < 8; ++j) {
                    float4 bv = *(const float4*)&bolb[j * 16 + quad * 4];
                    bl[j][0] = bv.x; bl[j][1] = bv.y; bl[j][2] = bv.z; bl[j][3] = bv.w;
                }
                // 8 output tiles, K=128
                f32x4_t acc[8];
#pragma unroll
                for (int j = 0; j < 8; ++j) {
                    acc[j] = (f32x4_t){0.f, 0.f, 0.f, 0.f};
#pragma unroll
                    for (int kt = 0; kt < 4; ++kt)
                        acc[j] = mfma16(ldfrag(&wodeb[j * 16 + l15][kt * 32 + quad * 8]),
                                        zf[kt], acc[j]);
                }
                float kf[8][4];
#pragma unroll
                for (int j = 0; j < 8; ++j)
#pragma unroll
                    for (int i = 0; i < 4; ++i)
                        kf[j][i] = tanhfast(acc[j][i], bl[j][i]);
                if (s < 5) {
#pragma unroll
                    for (int j = 0; j < 8; ++j) {
                        kp[s][j][0] = packbf2(kf[j][0], kf[j][1]);
                        kp[s][j][1] = packbf2(kf[j][2], kf[j][3]);
                    }
                }
                // y accumulation uses only FRESH f32 k's (full precision)
#pragma unroll
                for (int j = 0; j < 8; ++j)
#pragma unroll
                    for (int i = 0; i < 4; ++i) {
                        if (s == 0)      yn[j][i] = fmaf(e0, kf[j][i], y[j][i]);
                        else if (s == 2) yn[j][i] = fmaf(e2, kf[j][i], yn[j][i]);
                        else if (s == 3) yn[j][i] = fmaf(e3, kf[j][i], yn[j][i]);
                        else if (s == 4) yn[j][i] = fmaf(e4, kf[j][i], yn[j][i]);
                        else if (s == 5) y[j][i]  = fmaf(e5, kf[j][i], yn[j][i]);
                    }
                // next z (stage combos use stored bf16 k's -- z is bf16-bound anyway)
#pragma unroll
                for (int j = 0; j < 8; ++j) {
                    float zv[4];
#pragma unroll
                    for (int i = 0; i < 4; ++i) {
                        unsigned int h = i >> 1;
                        float k0 = (i & 1) ? upk_hi(kp[0][j][h]) : upk_lo(kp[0][j][h]);
                        float k1 = (i & 1) ? upk_hi(kp[1][j][h]) : upk_lo(kp[1][j][h]);
                        float k2 = (i & 1) ? upk_hi(kp[2][j][h]) : upk_lo(kp[2][j][h]);
                        float k3 = (i & 1) ? upk_hi(kp[3][j][h]) : upk_lo(kp[3][j][h]);
                        float zvv;
                        if (s == 0)      zvv = fmaf(d10, kf[j][i], y[j][i]);
                        else if (s == 1) zvv = y[j][i] + d20 * k0 + d21 * kf[j][i];
                        else if (s == 2) zvv = y[j][i] + d30 * k0 + d31 * k1 + d32 * kf[j][i];
                        else if (s == 3) zvv = y[j][i] + d40 * k0 + d41 * k1
                                             + d42 * k2 + d43 * kf[j][i];
                        else if (s == 4) zvv = y[j][i] + d50 * k0 + d51 * k1
                                             + d52 * k2 + d53 * k3 + d54 * kf[j][i];
                        else             zvv = y[j][i];   // s==5: z_next = y_{t+1}
                        zv[i] = zvv;
                    }
                    uint2 pk = pack4(zv[0], zv[1], zv[2], zv[3]);
                    *(uint2*)&zb[l15][j * 16 + quad * 4] = pk;
                    if (s == 5)
                        stg8(yTraj + ((size_t)(t + 1) * 1024 + row) * CTOT + j * 16 + quad * 4, pk);
                }
                if (s == 2) {   // deferred drain+release: t's stores are 3 stages old
                    asm volatile("s_waitcnt vmcnt(0)" ::: "memory");
                    if (lane == 0)
                        __hip_atomic_store(&yflag[c * 128 + t], YMAGIC(t),
                                           __ATOMIC_RELAXED, __HIP_MEMORY_SCOPE_AGENT);
                }
            }
        }
        asm volatile("s_waitcnt vmcnt(0)" ::: "memory");
        if (lane == 0)
            __hip_atomic_store(&yflag[c * 128 + 95], YMAGIC(95),
                               __ATOMIC_RELAXED, __HIP_MEMORY_SCOPE_AGENT);
        return;
    }

    // ==================== GRU consumer roles ==================================
    const float* Wih = (role == 1) ? Wih0 : Wih1;
    const float* Whh = (role == 1) ? Whh0 : Whh1;
    const float* bih = (role == 1) ? bih0 : bih1;
    const float* bhh = (role == 1) ? bhh0 : bhh1;
    const unsigned short* src = (role == 1) ? yTraj : h1Traj;

    bf16x8_t wih[3][4], whh[3][4];
#pragma unroll
    for (int g = 0; g < 3; ++g)
#pragma unroll
        for (int kt = 0; kt < 4; ++kt) {
            wih[g][kt] = ldfragW(Wih + (size_t)(g * 128 + wv * 16 + l15) * CTOT + kt * 32 + quad * 8);
            whh[g][kt] = ldfragW(Whh + (size_t)(g * 128 + wv * 16 + l15) * CTOT + kt * 32 + quad * 8);
        }
    float br[4], bz[4], bin_[4], bhn[4];
    {
        float4 a0 = *(const float4*)(bih + 0 * 128 + fbase);
        float4 b0 = *(const float4*)(bhh + 0 * 128 + fbase);
        float4 a1 = *(const float4*)(bih + 1 * 128 + fbase);
        float4 b1 = *(const float4*)(bhh + 1 * 128 + fbase);
        float4 a2 = *(const float4*)(bih + 2 * 128 + fbase);
        float4 b2 = *(const float4*)(bhh + 2 * 128 + fbase);
        br[0] = a0.x + b0.x; br[1] = a0.y + b0.y; br[2] = a0.z + b0.z; br[3] = a0.w + b0.w;
        bz[0] = a1.x + b1.x; bz[1] = a1.y + b1.y; bz[2] = a1.z + b1.z; bz[3] = a1.w + b1.w;
        bin_[0] = a2.x; bin_[1] = a2.y; bin_[2] = a2.z; bin_[3] = a2.w;
        bhn[0] = b2.x; bhn[1] = b2.y; bhn[2] = b2.z; bhn[3] = b2.w;
    }

    float h[4] = {0.f, 0.f, 0.f, 0.f};
    *(uint2*)&zbuf[0][l15][fbase] = pack4(0.f, 0.f, 0.f, 0.f);
    int p = 0;
    __syncthreads();

    if (role == 1) {
#pragma unroll 1
        for (int t = 0; t < TPTS; ++t) {
            // h-part MFMAs first: independent of the incoming x_t -> overlaps
            // the flag poll / store-drain dead time.
            bf16x8_t ah[4];
#pragma unroll
            for (int kt = 0; kt < 4; ++kt)
                ah[kt] = ldfrag(&zbuf[p][l15][kt * 32 + quad * 8]);
            f32x4_t gh[3];
#pragma unroll
            for (int g = 0; g < 3; ++g) gh[g] = (f32x4_t){0.f, 0.f, 0.f, 0.f};
#pragma unroll
            for (int kt = 0; kt < 4; ++kt) {
                gh[0] = mfma16(whh[0][kt], ah[kt], gh[0]);
                gh[1] = mfma16(whh[1][kt], ah[kt], gh[1]);
                gh[2] = mfma16(whh[2][kt], ah[kt], gh[2]);
            }
            asm volatile("s_waitcnt vmcnt(0)" ::: "memory");   // drain t-1 h1 store
            __builtin_amdgcn_s_barrier();                      // all waves drained
            if (tid == 0) {
                if (t > 0)
                    __hip_atomic_store(&h1flag[c * 128 + (t - 1)], H1MAGIC(t - 1),
                                       __ATOMIC_RELAXED, __HIP_MEMORY_SCOPE_AGENT);
                int guard = 0;
                while (__hip_atomic_load(&yflag[c * 128 + t],
                                         __ATOMIC_RELAXED, __HIP_MEMORY_SCOPE_AGENT) != YMAGIC(t)) {
                    __builtin_amdgcn_s_sleep(1);
                    if (++guard > (1 << 22)) break;
                }
            }
            __syncthreads();
            const unsigned short* xp = src + ((size_t)t * 1024 + rbase + l15) * CTOT;
            bf16x8_t ax[4];
#pragma unroll
            for (int kt = 0; kt < 4; ++kt) ax[kt] = ldfragG(xp + kt * 32 + quad * 8);
            f32x4_t gx[3];
#pragma unroll
            for (int g = 0; g < 3; ++g) gx[g] = (f32x4_t){0.f, 0.f, 0.f, 0.f};
#pragma unroll
            for (int kt = 0; kt < 4; ++kt) {
                gx[0] = mfma16(wih[0][kt], ax[kt], gx[0]);
                gx[1] = mfma16(wih[1][kt], ax[kt], gx[1]);
                gx[2] = mfma16(wih[2][kt], ax[kt], gx[2]);
            }
#pragma unroll
            for (int i = 0; i < 4; ++i) {
                float rr = sigm(gx[0][i] + gh[0][i] + br[i]);
                float zz = sigm(gx[1][i] + gh[1][i] + bz[i]);
                float nn = tanh2((gx[2][i] + bin_[i]) + rr * (gh[2][i] + bhn[i]));
                h[i] = nn + zz * (h[i] - nn);
            }
            uint2 pk = pack4(h[0], h[1], h[2], h[3]);
            *(uint2*)&zbuf[p ^ 1][l15][fbase] = pk;
            stg8(h1Traj + ((size_t)t * 1024 + rbase + l15) * CTOT + fbase, pk);
            LGKM_BAR();          // LDS handoff only; h1 store drains next iter
            p ^= 1;
        }
        asm volatile("s_waitcnt vmcnt(0)" ::: "memory");
        __syncthreads();
        if (tid == 0)
            __hip_atomic_store(&h1flag[c * 128 + (TPTS - 1)], H1MAGIC(TPTS - 1),
                               __ATOMIC_RELAXED, __HIP_MEMORY_SCOPE_AGENT);
        return;
    }

    // role 2: GRU1 (no global stores in loop) + MLP head
#pragma unroll 1
    for (int t = 0; t < TPTS; ++t) {
        bf16x8_t ah[4];
#pragma unroll
        for (int kt = 0; kt < 4; ++kt)
            ah[kt] = ldfrag(&zbuf[p][l15][kt * 32 + quad * 8]);
        f32x4_t gh[3];
#pragma unroll
        for (int g = 0; g < 3; ++g) gh[g] = (f32x4_t){0.f, 0.f, 0.f, 0.f};
#pragma unroll
        for (int kt = 0; kt < 4; ++kt) {
            gh[0] = mfma16(whh[0][kt], ah[kt], gh[0]);
            gh[1] = mfma16(whh[1][kt], ah[kt], gh[1]);
            gh[2] = mfma16(whh[2][kt], ah[kt], gh[2]);
        }
        waitflag(&h1flag[c * 128 + t], H1MAGIC(t));
        const unsigned short* xp = src + ((size_t)t * 1024 + rbase + l15) * CTOT;
        bf16x8_t ax[4];
#pragma unroll
        for (int kt = 0; kt < 4; ++kt) ax[kt] = ldfragG(xp + kt * 32 + quad * 8);
        f32x4_t gx[3];
#pragma unroll
        for (int g = 0; g < 3; ++g) gx[g] = (f32x4_t){0.f, 0.f, 0.f, 0.f};
#pragma unroll
        for (int kt = 0; kt < 4; ++kt) {
            gx[0] = mfma16(wih[0][kt], ax[kt], gx[0]);
            gx[1] = mfma16(wih[1][kt], ax[kt], gx[1]);
            gx[2] = mfma16(wih[2][kt], ax[kt], gx[2]);
        }
#pragma unroll
        for (int i = 0; i < 4; ++i) {
            float rr = sigm(gx[0][i] + gh[0][i] + br[i]);
            float zz = sigm(gx[1][i] + gh[1][i] + bz[i]);
            float nn = tanh2((gx[2][i] + bin_[i]) + rr * (gh[2][i] + bhn[i]));
            h[i] = nn + zz * (h[i] - nn);
        }
        *(uint2*)&zbuf[p ^ 1][l15][fbase] = pack4(h[0], h[1], h[2], h[3]);
        LGKM_BAR();
        p ^= 1;
    }

    // ==================== MLP head (role 2) ===================================
    if (wv < 4) {
        bf16x8_t wf[4], hf[4];
#pragma unroll
        for (int kt = 0; kt < 4; ++kt) {
            wf[kt] = ldfragW(W1v + (size_t)(wv * 16 + l15) * CTOT + kt * 32 + quad * 8);
            hf[kt] = ldfrag(&zbuf[p][l15][kt * 32 + quad * 8]);
        }
        f32x4_t acc = {0.f, 0.f, 0.f, 0.f};
#pragma unroll
        for (int kt = 0; kt < 4; ++kt) acc = mfma16(wf[kt], hf[kt], acc);
        float4 bb = *(const float4*)(b1v + wv * 16 + quad * 4);
        const float* bbp = (const float*)&bb;
        float gl[4];
#pragma unroll
        for (int i = 0; i < 4; ++i) {
            float x = acc[i] + bbp[i];
            gl[i] = 0.5f * x * (1.0f + erff(x * 0.70710678118654752f));
        }
        *(uint2*)&hidbuf[l15][wv * 16 + quad * 4] = pack4(gl[0], gl[1], gl[2], gl[3]);
    }
    __syncthreads();

    bf16x8_t ahid[2];
#pragma unroll
    for (int kt = 0; kt < 2; ++kt)
        ahid[kt] = ldfrag(&hidbuf[l15][kt * 32 + quad * 8]);
#pragma unroll 1
    for (int j = 0; j < 24; ++j) {
        int mt2 = wv * 24 + j;
        bf16x8_t wf0 = ldfragW(W2v + (size_t)(mt2 * 16 + l15) * 64 + quad * 8);
        bf16x8_t wf1 = ldfragW(W2v + (size_t)(mt2 * 16 + l15) * 64 + 32 + quad * 8);
        float4 bv = *(const float4*)(b2v + mt2 * 16 + quad * 4);
        const float* bvp = (const float*)&bv;
        f32x4_t acc = {0.f, 0.f, 0.f, 0.f};
        acc = mfma16(wf0, ahid[0], acc);
        acc = mfma16(wf1, ahid[1], acc);
        float4 o;
        o.x = acc[0] + bvp[0]; o.y = acc[1] + bvp[1];
        o.z = acc[2] + bvp[2]; o.w = acc[3] + bvp[3];
        *(float4*)(outp + (size_t)(rbase + l15) * 3072 + mt2 * 16 + quad * 4) = o;
    }
#undef YMAGIC
#undef H1MAGIC
}

extern "C" void kernel_launch(void* const* d_in, const int* in_sizes, int n_in,
                              void* d_out, int out_size, void* d_ws, size_t ws_size,
                              hipStream_t stream) {
    // setup_inputs order: 0:x(unused) 1:yl 2:yh 3:W_ode 4:b_ode 5:W_ih0 6:W_hh0
    // 7:b_ih0 8:b_hh0 9:W_ih1 10:W_hh1 11:b_ih1 12:b_hh1 13:W1 14:b1 15:W2 16:b2
    const float* yl   = (const float*)d_in[1];
    const float* yh   = (const float*)d_in[2];
    const float* Wode = (const float*)d_in[3];
    const float* bode = (const float*)d_in[4];
    const float* Wih0 = (const float*)d_in[5];
    const float* Whh0 = (const float*)d_in[6];
    const float* bih0 = (const float*)d_in[7];
    const float* bhh0 = (const float*)d_in[8];
    const float* Wih1 = (const float*)d_in[9];
    const float* Whh1 = (const float*)d_in[10];
    const float* bih1 = (const float*)d_in[11];
    const float* bhh1 = (const float*)d_in[12];
    const float* W1v  = (const float*)d_in[13];
    const float* b1v  = (const float*)d_in[14];
    const float* W2v  = (const float*)d_in[15];
    const float* b2v  = (const float*)d_in[16];

    ode_forecaster<<<dim3(192), dim3(512), 0, stream>>>(
        yl, yh, Wode, bode, Wih0, Whh0, bih0, bhh0,
        Wih1, Whh1, bih1, bhh1, W1v, b1v, W2v, b2v,
        (float*)d_out, (char*)d_ws);
}

// Round 4
// 1334.775 us; speedup vs baseline: 1.8207x; 1.8207x over previous
//
#include <hip/hip_runtime.h>
#include <hip/hip_bf16.h>
#include <math.h>

#define TPTS 96
#define CTOT 128
#define LDP 134   // LDS row pitch u16: <=2-way banks (verified R4: conflicts ~0)

typedef __bf16 bf16x8_t __attribute__((ext_vector_type(8)));
typedef float f32x4_t __attribute__((ext_vector_type(4)));
typedef unsigned short us8_t __attribute__((ext_vector_type(8)));

__device__ __forceinline__ unsigned short f2b(float f) {
    union { float f; unsigned int i; } v; v.f = f;
    unsigned int r = v.i + 0x7fffu + ((v.i >> 16) & 1u);
    return (unsigned short)(r >> 16);
}
// HW packed bf16 convert (RNE, matches f2b for finite inputs).
__device__ __forceinline__ unsigned int packbf2(float a, float b) {
    unsigned int r;
    asm("v_cvt_pk_bf16_f32 %0, %1, %2" : "=v"(r) : "v"(a), "v"(b));
    return r;
}
__device__ __forceinline__ uint2 pack4(float v0, float v1, float v2, float v3) {
    uint2 w; w.x = packbf2(v0, v1); w.y = packbf2(v2, v3); return w;
}
// unpack bf16 pair -> f32 (1 VALU op each)
__device__ __forceinline__ float upk_lo(unsigned int w) {
    return __builtin_bit_cast(float, w << 16);
}
__device__ __forceinline__ float upk_hi(unsigned int w) {
    return __builtin_bit_cast(float, w & 0xffff0000u);
}
// static-index extract of element i from a packed uint2 (4 bf16)
__device__ __forceinline__ float upk4(uint2 k, int i) {
    unsigned int w = (i >> 1) ? k.y : k.x;
    return (i & 1) ? upk_hi(w) : upk_lo(w);
}
__device__ __forceinline__ f32x4_t mfma16(bf16x8_t a, bf16x8_t b, f32x4_t c) {
    return __builtin_amdgcn_mfma_f32_16x16x32_bf16(a, b, c, 0, 0, 0);
}
__device__ __forceinline__ bf16x8_t ldfrag(const unsigned short* p) {
    us8_t v = *(const us8_t*)p;
    return __builtin_bit_cast(bf16x8_t, v);
}
// Cross-XCD coherent fragment load (relaxed agent atomics -> LLC, no cache inv)
__device__ __forceinline__ bf16x8_t ldfragG(const unsigned short* p) {
    union { unsigned long long q[2]; us8_t v; } u;
    u.q[0] = __hip_atomic_load((const unsigned long long*)p,
                               __ATOMIC_RELAXED, __HIP_MEMORY_SCOPE_AGENT);
    u.q[1] = __hip_atomic_load((const unsigned long long*)(p + 4),
                               __ATOMIC_RELAXED, __HIP_MEMORY_SCOPE_AGENT);
    return __builtin_bit_cast(bf16x8_t, u.v);
}
// Cross-XCD coherent 8B store: write-through to LLC (chip coherence point).
__device__ __forceinline__ void stg8(unsigned short* p, uint2 pk) {
    unsigned long long q = ((unsigned long long)pk.y << 32) | (unsigned long long)pk.x;
    __hip_atomic_store((unsigned long long*)p, q,
                       __ATOMIC_RELAXED, __HIP_MEMORY_SCOPE_AGENT);
}
__device__ __forceinline__ bf16x8_t ldfragW(const float* p) {
    float4 a = *(const float4*)p;
    float4 b = *(const float4*)(p + 4);
    bf16x8_t r;
    r[0] = __builtin_bit_cast(__bf16, f2b(a.x)); r[1] = __builtin_bit_cast(__bf16, f2b(a.y));
    r[2] = __builtin_bit_cast(__bf16, f2b(a.z)); r[3] = __builtin_bit_cast(__bf16, f2b(a.w));
    r[4] = __builtin_bit_cast(__bf16, f2b(b.x)); r[5] = __builtin_bit_cast(__bf16, f2b(b.y));
    r[6] = __builtin_bit_cast(__bf16, f2b(b.z)); r[7] = __builtin_bit_cast(__bf16, f2b(b.w));
    return r;
}
__device__ __forceinline__ float tanh2(float x) {   // finite inputs only
    float e = __expf(x + x);
    return 1.f - __fdividef(2.f, e + 1.f);
}
#define TWO_LOG2E 2.8853900817779268f
__device__ __forceinline__ float tanhfast(float acc, float bl) {
    float e = __builtin_amdgcn_exp2f(fmaf(acc, TWO_LOG2E, bl));  // exp(2(acc+bo))
    float r = __builtin_amdgcn_rcpf(e + 1.f);
    return fmaf(-2.f, r, 1.f);
}
__device__ __forceinline__ float sigm(float x) {
    return __fdividef(1.f, 1.f + __expf(-x));
}

// Raw barrier: LDS-drain only (keeps global stores draining off-path).
#define LGKM_BAR() do {                                         \
        asm volatile("s_waitcnt lgkmcnt(0)" ::: "memory");      \
        __builtin_amdgcn_s_barrier();                           \
    } while (0)

__device__ __forceinline__ void waitflag(unsigned int* f, unsigned int want) {
    if (threadIdx.x == 0) {
        int guard = 0;
        while (__hip_atomic_load(f, __ATOMIC_RELAXED, __HIP_MEMORY_SCOPE_AGENT) != want) {
            __builtin_amdgcn_s_sleep(1);
            if (++guard > (1 << 22)) break;   // hang-proof: degrade, don't wedge
        }
    }
    __syncthreads();
}

// R8: 192 blocks x 512 thr, role = blockIdx>>6.
// role 0: single-wave, barrier-free ODE producer, SPILL-PROOF this time:
//   Wode bf16 in LDS (staged by all 8 waves), k1..k4 packed bf16 in LDS,
//   z double-buffered in LDS; registers hold only y/yn (64), bias (32),
//   acc (32), z-frags (16) -> ~165 VGPR, under the 256 cap.
// role 1/2: GRU0 / GRU1+head (R2-proven structure, gh hoisted over the poll).
// LDS is a carved union: producer layout 60KB, GRU layout 11KB.
__global__ void __launch_bounds__(512, 1)
ode_forecaster(const float* __restrict__ yl,
               const float* __restrict__ yh,
               const float* __restrict__ Wode,
               const float* __restrict__ bode,
               const float* __restrict__ Wih0,
               const float* __restrict__ Whh0,
               const float* __restrict__ bih0,
               const float* __restrict__ bhh0,
               const float* __restrict__ Wih1,
               const float* __restrict__ Whh1,
               const float* __restrict__ bih1,
               const float* __restrict__ bhh1,
               const float* __restrict__ W1v,
               const float* __restrict__ b1v,
               const float* __restrict__ W2v,
               const float* __restrict__ b2v,
               float* __restrict__ outp,
               char* __restrict__ wsb)
{
    const int role = blockIdx.x >> 6;
    const int c    = blockIdx.x & 63;
    const int tid  = threadIdx.x, lane = tid & 63, wv = tid >> 6;
    const int l15  = lane & 15, quad = lane >> 4;
    const int fbase = wv * 16 + quad * 4;
    const int rbase = c * 16;

    __shared__ __align__(16) char smem[60416];
    // producer carve (60288 B)
    unsigned short (*wodeb)[134]     = reinterpret_cast<unsigned short (*)[134]>(smem);            // [128][134]
    unsigned short (*zb)[16][134]    = reinterpret_cast<unsigned short (*)[16][134]>(smem + 34304); // [2][16][134]
    unsigned short (*kb)[16][132]    = reinterpret_cast<unsigned short (*)[16][132]>(smem + 42880); // [4][16][132]
    float* bolb                      = reinterpret_cast<float*>(smem + 59776);                      // [128]
    // GRU carve (10880 B)
    unsigned short (*zbuf)[16][LDP]  = reinterpret_cast<unsigned short (*)[16][LDP]>(smem);         // [2][16][134]
    unsigned short (*hidbuf)[72]     = reinterpret_cast<unsigned short (*)[72]>(smem + 8576);       // [16][72]

    unsigned short* yTraj  = (unsigned short*)(wsb);
    unsigned short* h1Traj = (unsigned short*)(wsb + 0x2000000);
    unsigned int*   yflag  = (unsigned int*)(wsb + 0x4000000);
    unsigned int*   h1flag = (unsigned int*)(wsb + 0x4010000);
#define YMAGIC(t)  (0x5E000000u + (unsigned)(t))
#define H1MAGIC(t) (0x6E000000u + (unsigned)(t))

    if (role == 0) {
        // ---- all 8 waves stage Wode f32 -> LDS bf16 + bias ----
        {
            int r = tid >> 2, c0 = (tid & 3) * 32;
            const float* wrow = Wode + r * CTOT + c0;
#pragma unroll
            for (int u = 0; u < 32; u += 8) {
                float4 a = *(const float4*)(wrow + u);
                float4 b = *(const float4*)(wrow + u + 4);
                *(uint2*)&wodeb[r][c0 + u]     = pack4(a.x, a.y, a.z, a.w);
                *(uint2*)&wodeb[r][c0 + u + 4] = pack4(b.x, b.y, b.z, b.w);
            }
            if (tid < 128) bolb[tid] = bode[tid] * TWO_LOG2E;
        }

        // ---- wave 0 preps slice state ----
        const int row = rbase + l15;
        float y[8][4], yn[8][4];
        if (wv == 0) {
#pragma unroll
            for (int j = 0; j < 8; ++j) {
#pragma unroll
                for (int i = 0; i < 4; ++i) {
                    int f = j * 16 + quad * 4 + i;
                    y[j][i] = (f < 32) ? yl[row * 32 + f] : yh[row * 96 + (f - 32)];
                }
                uint2 pk = pack4(y[j][0], y[j][1], y[j][2], y[j][3]);
                *(uint2*)&zb[0][l15][j * 16 + quad * 4] = pk;
                stg8(yTraj + ((size_t)row) * CTOT + j * 16 + quad * 4, pk);
            }
        }
        __syncthreads();
        if (wv != 0) return;   // 7 waves exit; wave 0 runs barrier-free

        asm volatile("s_waitcnt vmcnt(0)" ::: "memory");
        if (lane == 0)
            __hip_atomic_store(&yflag[c * 128 + 0], YMAGIC(0),
                               __ATOMIC_RELAXED, __HIP_MEMORY_SCOPE_AGENT);

        // bias (pre-scaled) into registers: 32 VGPR
        float bl[8][4];
#pragma unroll
        for (int j = 0; j < 8; ++j) {
            float4 bv = *(const float4*)&bolb[j * 16 + quad * 4];
            bl[j][0] = bv.x; bl[j][1] = bv.y; bl[j][2] = bv.z; bl[j][3] = bv.w;
        }

        // dt-folded Dormand-Prince coefficients
        const float dt = 1.0f / 95.0f;
        const float d10 = dt * 0.2f;
        const float d20 = dt * (3.f/40.f),  d21 = dt * (9.f/40.f);
        const float d30 = dt * (44.f/45.f), d31 = dt * (-56.f/15.f), d32 = dt * (32.f/9.f);
        const float d40 = dt * (19372.f/6561.f), d41 = dt * (-25360.f/2187.f),
                    d42 = dt * (64448.f/6561.f), d43 = dt * (-212.f/729.f);
        const float d50 = dt * (9017.f/3168.f), d51 = dt * (-355.f/33.f),
                    d52 = dt * (46732.f/5247.f), d53 = dt * (49.f/176.f),
                    d54 = dt * (-5103.f/18656.f);
        const float e0 = dt * (35.f/384.f), e2 = dt * (500.f/1113.f), e3 = dt * (125.f/192.f),
                    e4 = dt * (-2187.f/6784.f), e5 = dt * (11.f/84.f);

        int pz = 0;
#pragma unroll 1
        for (int t = 0; t < 95; ++t) {
#pragma unroll
            for (int s = 0; s < 6; ++s) {
                // B-frags of current z (written by previous stage, same wave:
                // compiler inserts the lgkmcnt RAW wait, no barrier needed)
                bf16x8_t zf[4];
#pragma unroll
                for (int kt = 0; kt < 4; ++kt)
                    zf[kt] = ldfrag(&zb[pz][l15][kt * 32 + quad * 8]);
                // 8 col-tiles x 4 k-frags, interleaved so the 32 MFMAs pipeline
                f32x4_t acc[8];
#pragma unroll
                for (int j = 0; j < 8; ++j) acc[j] = (f32x4_t){0.f, 0.f, 0.f, 0.f};
#pragma unroll
                for (int kt = 0; kt < 4; ++kt)
#pragma unroll
                    for (int j = 0; j < 8; ++j)
                        acc[j] = mfma16(ldfrag(&wodeb[j * 16 + l15][kt * 32 + quad * 8]),
                                        zf[kt], acc[j]);
#pragma unroll
                for (int j = 0; j < 8; ++j) {
                    float kf[4];
#pragma unroll
                    for (int i = 0; i < 4; ++i) kf[i] = tanhfast(acc[j][i], bl[j][i]);
                    if (s <= 3)   // k1..k4 kept as packed bf16 in LDS
                        *(uint2*)&kb[s][l15][j * 16 + quad * 4]
                            = pack4(kf[0], kf[1], kf[2], kf[3]);
                    // y accumulation uses only FRESH f32 k's (full precision)
#pragma unroll
                    for (int i = 0; i < 4; ++i) {
                        if (s == 0)      yn[j][i] = fmaf(e0, kf[i], y[j][i]);
                        else if (s == 2) yn[j][i] = fmaf(e2, kf[i], yn[j][i]);
                        else if (s == 3) yn[j][i] = fmaf(e3, kf[i], yn[j][i]);
                        else if (s == 4) yn[j][i] = fmaf(e4, kf[i], yn[j][i]);
                        else if (s == 5) y[j][i]  = fmaf(e5, kf[i], yn[j][i]);
                    }
                    // next z (combos use stored bf16 k's -- z is bf16-bound anyway)
                    float zv[4];
                    if (s == 0) {
#pragma unroll
                        for (int i = 0; i < 4; ++i) zv[i] = fmaf(d10, kf[i], y[j][i]);
                    } else if (s == 1) {
                        uint2 k0 = *(uint2*)&kb[0][l15][j * 16 + quad * 4];
#pragma unroll
                        for (int i = 0; i < 4; ++i)
                            zv[i] = fmaf(d21, kf[i], fmaf(d20, upk4(k0, i), y[j][i]));
                    } else if (s == 2) {
                        uint2 k0 = *(uint2*)&kb[0][l15][j * 16 + quad * 4];
                        uint2 k1 = *(uint2*)&kb[1][l15][j * 16 + quad * 4];
#pragma unroll
                        for (int i = 0; i < 4; ++i)
                            zv[i] = fmaf(d32, kf[i], fmaf(d31, upk4(k1, i),
                                    fmaf(d30, upk4(k0, i), y[j][i])));
                    } else if (s == 3) {
                        uint2 k0 = *(uint2*)&kb[0][l15][j * 16 + quad * 4];
                        uint2 k1 = *(uint2*)&kb[1][l15][j * 16 + quad * 4];
                        uint2 k2 = *(uint2*)&kb[2][l15][j * 16 + quad * 4];
#pragma unroll
                        for (int i = 0; i < 4; ++i)
                            zv[i] = fmaf(d43, kf[i], fmaf(d42, upk4(k2, i),
                                    fmaf(d41, upk4(k1, i), fmaf(d40, upk4(k0, i), y[j][i]))));
                    } else if (s == 4) {
                        uint2 k0 = *(uint2*)&kb[0][l15][j * 16 + quad * 4];
                        uint2 k1 = *(uint2*)&kb[1][l15][j * 16 + quad * 4];
                        uint2 k2 = *(uint2*)&kb[2][l15][j * 16 + quad * 4];
                        uint2 k3 = *(uint2*)&kb[3][l15][j * 16 + quad * 4];
#pragma unroll
                        for (int i = 0; i < 4; ++i)
                            zv[i] = fmaf(d54, kf[i], fmaf(d53, upk4(k3, i),
                                    fmaf(d52, upk4(k2, i), fmaf(d51, upk4(k1, i),
                                    fmaf(d50, upk4(k0, i), y[j][i])))));
                    } else {
#pragma unroll
                        for (int i = 0; i < 4; ++i) zv[i] = y[j][i];   // z_next = y_{t+1}
                    }
                    uint2 pk = pack4(zv[0], zv[1], zv[2], zv[3]);
                    *(uint2*)&zb[pz ^ 1][l15][j * 16 + quad * 4] = pk;
                    if (s == 5)
                        stg8(yTraj + ((size_t)(t + 1) * 1024 + row) * CTOT + j * 16 + quad * 4, pk);
                }
                if (s == 2) {   // deferred drain+release: t's stores are 3 stages old
                    asm volatile("s_waitcnt vmcnt(0)" ::: "memory");
                    if (lane == 0)
                        __hip_atomic_store(&yflag[c * 128 + t], YMAGIC(t),
                                           __ATOMIC_RELAXED, __HIP_MEMORY_SCOPE_AGENT);
                }
                pz ^= 1;
            }
        }
        asm volatile("s_waitcnt vmcnt(0)" ::: "memory");
        if (lane == 0)
            __hip_atomic_store(&yflag[c * 128 + 95], YMAGIC(95),
                               __ATOMIC_RELAXED, __HIP_MEMORY_SCOPE_AGENT);
        return;
    }

    // ==================== GRU consumer roles ==================================
    const float* Wih = (role == 1) ? Wih0 : Wih1;
    const float* Whh = (role == 1) ? Whh0 : Whh1;
    const float* bih = (role == 1) ? bih0 : bih1;
    const float* bhh = (role == 1) ? bhh0 : bhh1;
    const unsigned short* src = (role == 1) ? yTraj : h1Traj;

    bf16x8_t wih[3][4], whh[3][4];
#pragma unroll
    for (int g = 0; g < 3; ++g)
#pragma unroll
        for (int kt = 0; kt < 4; ++kt) {
            wih[g][kt] = ldfragW(Wih + (size_t)(g * 128 + wv * 16 + l15) * CTOT + kt * 32 + quad * 8);
            whh[g][kt] = ldfragW(Whh + (size_t)(g * 128 + wv * 16 + l15) * CTOT + kt * 32 + quad * 8);
        }
    float br[4], bz[4], bin_[4], bhn[4];
    {
        float4 a0 = *(const float4*)(bih + 0 * 128 + fbase);
        float4 b0 = *(const float4*)(bhh + 0 * 128 + fbase);
        float4 a1 = *(const float4*)(bih + 1 * 128 + fbase);
        float4 b1 = *(const float4*)(bhh + 1 * 128 + fbase);
        float4 a2 = *(const float4*)(bih + 2 * 128 + fbase);
        float4 b2 = *(const float4*)(bhh + 2 * 128 + fbase);
        br[0] = a0.x + b0.x; br[1] = a0.y + b0.y; br[2] = a0.z + b0.z; br[3] = a0.w + b0.w;
        bz[0] = a1.x + b1.x; bz[1] = a1.y + b1.y; bz[2] = a1.z + b1.z; bz[3] = a1.w + b1.w;
        bin_[0] = a2.x; bin_[1] = a2.y; bin_[2] = a2.z; bin_[3] = a2.w;
        bhn[0] = b2.x; bhn[1] = b2.y; bhn[2] = b2.z; bhn[3] = b2.w;
    }

    float h[4] = {0.f, 0.f, 0.f, 0.f};
    *(uint2*)&zbuf[0][l15][fbase] = pack4(0.f, 0.f, 0.f, 0.f);
    int p = 0;
    __syncthreads();

    if (role == 1) {
#pragma unroll 1
        for (int t = 0; t < TPTS; ++t) {
            // h-part MFMAs first: independent of x_t -> overlaps flag-poll dead time
            bf16x8_t ah[4];
#pragma unroll
            for (int kt = 0; kt < 4; ++kt)
                ah[kt] = ldfrag(&zbuf[p][l15][kt * 32 + quad * 8]);
            f32x4_t gh[3];
#pragma unroll
            for (int g = 0; g < 3; ++g) gh[g] = (f32x4_t){0.f, 0.f, 0.f, 0.f};
#pragma unroll
            for (int kt = 0; kt < 4; ++kt) {
                gh[0] = mfma16(whh[0][kt], ah[kt], gh[0]);
                gh[1] = mfma16(whh[1][kt], ah[kt], gh[1]);
                gh[2] = mfma16(whh[2][kt], ah[kt], gh[2]);
            }
            asm volatile("s_waitcnt vmcnt(0)" ::: "memory");   // drain t-1 h1 store
            __builtin_amdgcn_s_barrier();                      // all waves drained
            if (tid == 0) {
                if (t > 0)
                    __hip_atomic_store(&h1flag[c * 128 + (t - 1)], H1MAGIC(t - 1),
                                       __ATOMIC_RELAXED, __HIP_MEMORY_SCOPE_AGENT);
                int guard = 0;
                while (__hip_atomic_load(&yflag[c * 128 + t],
                                         __ATOMIC_RELAXED, __HIP_MEMORY_SCOPE_AGENT) != YMAGIC(t)) {
                    __builtin_amdgcn_s_sleep(1);
                    if (++guard > (1 << 22)) break;
                }
            }
            __syncthreads();
            const unsigned short* xp = src + ((size_t)t * 1024 + rbase + l15) * CTOT;
            bf16x8_t ax[4];
#pragma unroll
            for (int kt = 0; kt < 4; ++kt) ax[kt] = ldfragG(xp + kt * 32 + quad * 8);
            f32x4_t gx[3];
#pragma unroll
            for (int g = 0; g < 3; ++g) gx[g] = (f32x4_t){0.f, 0.f, 0.f, 0.f};
#pragma unroll
            for (int kt = 0; kt < 4; ++kt) {
                gx[0] = mfma16(wih[0][kt], ax[kt], gx[0]);
                gx[1] = mfma16(wih[1][kt], ax[kt], gx[1]);
                gx[2] = mfma16(wih[2][kt], ax[kt], gx[2]);
            }
#pragma unroll
            for (int i = 0; i < 4; ++i) {
                float rr = sigm(gx[0][i] + gh[0][i] + br[i]);
                float zz = sigm(gx[1][i] + gh[1][i] + bz[i]);
                float nn = tanh2((gx[2][i] + bin_[i]) + rr * (gh[2][i] + bhn[i]));
                h[i] = nn + zz * (h[i] - nn);
            }
            uint2 pk = pack4(h[0], h[1], h[2], h[3]);
            *(uint2*)&zbuf[p ^ 1][l15][fbase] = pk;
            stg8(h1Traj + ((size_t)t * 1024 + rbase + l15) * CTOT + fbase, pk);
            LGKM_BAR();          // LDS handoff only; h1 store drains next iter
            p ^= 1;
        }
        asm volatile("s_waitcnt vmcnt(0)" ::: "memory");
        __syncthreads();
        if (tid == 0)
            __hip_atomic_store(&h1flag[c * 128 + (TPTS - 1)], H1MAGIC(TPTS - 1),
                               __ATOMIC_RELAXED, __HIP_MEMORY_SCOPE_AGENT);
        return;
    }

    // role 2: GRU1 (no global stores in loop) + MLP head
#pragma unroll 1
    for (int t = 0; t < TPTS; ++t) {
        bf16x8_t ah[4];
#pragma unroll
        for (int kt = 0; kt < 4; ++kt)
            ah[kt] = ldfrag(&zbuf[p][l15][kt * 32 + quad * 8]);
        f32x4_t gh[3];
#pragma unroll
        for (int g = 0; g < 3; ++g) gh[g] = (f32x4_t){0.f, 0.f, 0.f, 0.f};
#pragma unroll
        for (int kt = 0; kt < 4; ++kt) {
            gh[0] = mfma16(whh[0][kt], ah[kt], gh[0]);
            gh[1] = mfma16(whh[1][kt], ah[kt], gh[1]);
            gh[2] = mfma16(whh[2][kt], ah[kt], gh[2]);
        }
        waitflag(&h1flag[c * 128 + t], H1MAGIC(t));
        const unsigned short* xp = src + ((size_t)t * 1024 + rbase + l15) * CTOT;
        bf16x8_t ax[4];
#pragma unroll
        for (int kt = 0; kt < 4; ++kt) ax[kt] = ldfragG(xp + kt * 32 + quad * 8);
        f32x4_t gx[3];
#pragma unroll
        for (int g = 0; g < 3; ++g) gx[g] = (f32x4_t){0.f, 0.f, 0.f, 0.f};
#pragma unroll
        for (int kt = 0; kt < 4; ++kt) {
            gx[0] = mfma16(wih[0][kt], ax[kt], gx[0]);
            gx[1] = mfma16(wih[1][kt], ax[kt], gx[1]);
            gx[2] = mfma16(wih[2][kt], ax[kt], gx[2]);
        }
#pragma unroll
        for (int i = 0; i < 4; ++i) {
            float rr = sigm(gx[0][i] + gh[0][i] + br[i]);
            float zz = sigm(gx[1][i] + gh[1][i] + bz[i]);
            float nn = tanh2((gx[2][i] + bin_[i]) + rr * (gh[2][i] + bhn[i]));
            h[i] = nn + zz * (h[i] - nn);
        }
        *(uint2*)&zbuf[p ^ 1][l15][fbase] = pack4(h[0], h[1], h[2], h[3]);
        LGKM_BAR();
        p ^= 1;
    }

    // ==================== MLP head (role 2) ===================================
    if (wv < 4) {
        bf16x8_t wf[4], hf[4];
#pragma unroll
        for (int kt = 0; kt < 4; ++kt) {
            wf[kt] = ldfragW(W1v + (size_t)(wv * 16 + l15) * CTOT + kt * 32 + quad * 8);
            hf[kt] = ldfrag(&zbuf[p][l15][kt * 32 + quad * 8]);
        }
        f32x4_t acc = {0.f, 0.f, 0.f, 0.f};
#pragma unroll
        for (int kt = 0; kt < 4; ++kt) acc = mfma16(wf[kt], hf[kt], acc);
        float4 bb = *(const float4*)(b1v + wv * 16 + quad * 4);
        const float* bbp = (const float*)&bb;
        float gl[4];
#pragma unroll
        for (int i = 0; i < 4; ++i) {
            float x = acc[i] + bbp[i];
            gl[i] = 0.5f * x * (1.0f + erff(x * 0.70710678118654752f));
        }
        *(uint2*)&hidbuf[l15][wv * 16 + quad * 4] = pack4(gl[0], gl[1], gl[2], gl[3]);
    }
    __syncthreads();

    bf16x8_t ahid[2];
#pragma unroll
    for (int kt = 0; kt < 2; ++kt)
        ahid[kt] = ldfrag(&hidbuf[l15][kt * 32 + quad * 8]);
#pragma unroll 1
    for (int j = 0; j < 24; ++j) {
        int mt2 = wv * 24 + j;
        bf16x8_t wf0 = ldfragW(W2v + (size_t)(mt2 * 16 + l15) * 64 + quad * 8);
        bf16x8_t wf1 = ldfragW(W2v + (size_t)(mt2 * 16 + l15) * 64 + 32 + quad * 8);
        float4 bv = *(const float4*)(b2v + mt2 * 16 + quad * 4);
        const float* bvp = (const float*)&bv;
        f32x4_t acc = {0.f, 0.f, 0.f, 0.f};
        acc = mfma16(wf0, ahid[0], acc);
        acc = mfma16(wf1, ahid[1], acc);
        float4 o;
        o.x = acc[0] + bvp[0]; o.y = acc[1] + bvp[1];
        o.z = acc[2] + bvp[2]; o.w = acc[3] + bvp[3];
        *(float4*)(outp + (size_t)(rbase + l15) * 3072 + mt2 * 16 + quad * 4) = o;
    }
#undef YMAGIC
#undef H1MAGIC
}

extern "C" void kernel_launch(void* const* d_in, const int* in_sizes, int n_in,
                              void* d_out, int out_size, void* d_ws, size_t ws_size,
                              hipStream_t stream) {
    // setup_inputs order: 0:x(unused) 1:yl 2:yh 3:W_ode 4:b_ode 5:W_ih0 6:W_hh0
    // 7:b_ih0 8:b_hh0 9:W_ih1 10:W_hh1 11:b_ih1 12:b_hh1 13:W1 14:b1 15:W2 16:b2
    const float* yl   = (const float*)d_in[1];
    const float* yh   = (const float*)d_in[2];
    const float* Wode = (const float*)d_in[3];
    const float* bode = (const float*)d_in[4];
    const float* Wih0 = (const float*)d_in[5];
    const float* Whh0 = (const float*)d_in[6];
    const float* bih0 = (const float*)d_in[7];
    const float* bhh0 = (const float*)d_in[8];
    const float* Wih1 = (const float*)d_in[9];
    const float* Whh1 = (const float*)d_in[10];
    const float* bih1 = (const float*)d_in[11];
    const float* bhh1 = (const float*)d_in[12];
    const float* W1v  = (const float*)d_in[13];
    const float* b1v  = (const float*)d_in[14];
    const float* W2v  = (const float*)d_in[15];
    const float* b2v  = (const float*)d_in[16];

    ode_forecaster<<<dim3(192), dim3(512), 0, stream>>>(
        yl, yh, Wode, bode, Wih0, Whh0, bih0, bhh0,
        Wih1, Whh1, bih1, bhh1, W1v, b1v, W2v, b2v,
        (float*)d_out, (char*)d_ws);
}

// Round 5
// 1040.534 us; speedup vs baseline: 2.3356x; 1.2828x over previous
//
#include <hip/hip_runtime.h>
#include <hip/hip_bf16.h>
#include <math.h>

#define TPTS 96
#define CTOT 128
#define LDP 134   // LDS row pitch u16: stride 134*2=268B -> bank stride 67 (odd), conflict-free
#define NBAR 571  // producer barrier count: 95*6 in-loop + 1 final

typedef __bf16 bf16x8_t __attribute__((ext_vector_type(8)));
typedef float f32x4_t __attribute__((ext_vector_type(4)));
typedef unsigned short us8_t __attribute__((ext_vector_type(8)));

__device__ __forceinline__ unsigned short f2b(float f) {
    union { float f; unsigned int i; } v; v.f = f;
    unsigned int r = v.i + 0x7fffu + ((v.i >> 16) & 1u);
    return (unsigned short)(r >> 16);
}
// HW packed bf16 convert (RNE, matches f2b for finite inputs).
__device__ __forceinline__ unsigned int packbf2(float a, float b) {
    unsigned int r;
    asm("v_cvt_pk_bf16_f32 %0, %1, %2" : "=v"(r) : "v"(a), "v"(b));
    return r;
}
__device__ __forceinline__ uint2 pack4(float v0, float v1, float v2, float v3) {
    uint2 w; w.x = packbf2(v0, v1); w.y = packbf2(v2, v3); return w;
}
__device__ __forceinline__ f32x4_t mfma16(bf16x8_t a, bf16x8_t b, f32x4_t c) {
    return __builtin_amdgcn_mfma_f32_16x16x32_bf16(a, b, c, 0, 0, 0);
}
__device__ __forceinline__ bf16x8_t ldfrag(const unsigned short* p) {
    us8_t v = *(const us8_t*)p;
    return __builtin_bit_cast(bf16x8_t, v);
}
// Cross-XCD coherent fragment load (relaxed agent atomics -> LLC, no cache inv)
__device__ __forceinline__ bf16x8_t ldfragG(const unsigned short* p) {
    union { unsigned long long q[2]; us8_t v; } u;
    u.q[0] = __hip_atomic_load((const unsigned long long*)p,
                               __ATOMIC_RELAXED, __HIP_MEMORY_SCOPE_AGENT);
    u.q[1] = __hip_atomic_load((const unsigned long long*)(p + 4),
                               __ATOMIC_RELAXED, __HIP_MEMORY_SCOPE_AGENT);
    return __builtin_bit_cast(bf16x8_t, u.v);
}
// Cross-XCD coherent 8B store: write-through to LLC (chip coherence point).
__device__ __forceinline__ void stg8(unsigned short* p, uint2 pk) {
    unsigned long long q = ((unsigned long long)pk.y << 32) | (unsigned long long)pk.x;
    __hip_atomic_store((unsigned long long*)p, q,
                       __ATOMIC_RELAXED, __HIP_MEMORY_SCOPE_AGENT);
}
__device__ __forceinline__ bf16x8_t ldfragW(const float* p) {
    float4 a = *(const float4*)p;
    float4 b = *(const float4*)(p + 4);
    bf16x8_t r;
    r[0] = __builtin_bit_cast(__bf16, f2b(a.x)); r[1] = __builtin_bit_cast(__bf16, f2b(a.y));
    r[2] = __builtin_bit_cast(__bf16, f2b(a.z)); r[3] = __builtin_bit_cast(__bf16, f2b(a.w));
    r[4] = __builtin_bit_cast(__bf16, f2b(b.x)); r[5] = __builtin_bit_cast(__bf16, f2b(b.y));
    r[6] = __builtin_bit_cast(__bf16, f2b(b.z)); r[7] = __builtin_bit_cast(__bf16, f2b(b.w));
    return r;
}
__device__ __forceinline__ float tanh2(float x) {   // finite inputs only
    float e = __expf(x + x);
    return 1.f - __fdividef(2.f, e + 1.f);
}
#define TWO_LOG2E 2.8853900817779268f
__device__ __forceinline__ float tanhfast(float acc, float bl) {
    float e = __builtin_amdgcn_exp2f(fmaf(acc, TWO_LOG2E, bl));  // exp(2(acc+bo))
    float r = __builtin_amdgcn_rcpf(e + 1.f);
    return fmaf(-2.f, r, 1.f);
}
__device__ __forceinline__ float sigm(float x) {
    return __fdividef(1.f, 1.f + __expf(-x));
}

// Raw barrier: LDS-drain only (keeps global stores draining off-path).
#define LGKM_BAR() do {                                         \
        asm volatile("s_waitcnt lgkmcnt(0)" ::: "memory");      \
        __builtin_amdgcn_s_barrier();                           \
    } while (0)

__device__ __forceinline__ void waitflag(unsigned int* f, unsigned int want) {
    if (threadIdx.x == 0) {
        int guard = 0;
        while (__hip_atomic_load(f, __ATOMIC_RELAXED, __HIP_MEMORY_SCOPE_AGENT) != want) {
            __builtin_amdgcn_s_sleep(1);
            if (++guard > (1 << 22)) break;   // hang-proof: degrade, don't wedge
        }
    }
    __syncthreads();
}

// R9: 192 blocks x 512 thr, role = blockIdx>>6.
// role 0: 4-wave producer, ONE WAVE PER SIMD (minimizes per-SIMD issue on the
//   serial path: R2 had 2 producer waves/SIMD = 2x issue; R4 had all work on
//   1 SIMD = 4x). Each wave owns 32 output features (2 16-tiles); k1..k4 live
//   in f32 registers (no kb LDS, no pack/unpack VALU); z handoff via LDS with
//   1 barrier/stage. Waves 4-7 stage Wode then park in a matched barrier loop.
// role 1/2: GRU0 / GRU1+head (R2-proven); x-loads issued BEFORE gh MFMAs so
//   LLC load latency hides under compute.
__global__ void __launch_bounds__(512, 1)
ode_forecaster(const float* __restrict__ yl,
               const float* __restrict__ yh,
               const float* __restrict__ Wode,
               const float* __restrict__ bode,
               const float* __restrict__ Wih0,
               const float* __restrict__ Whh0,
               const float* __restrict__ bih0,
               const float* __restrict__ bhh0,
               const float* __restrict__ Wih1,
               const float* __restrict__ Whh1,
               const float* __restrict__ bih1,
               const float* __restrict__ bhh1,
               const float* __restrict__ W1v,
               const float* __restrict__ b1v,
               const float* __restrict__ W2v,
               const float* __restrict__ b2v,
               float* __restrict__ outp,
               char* __restrict__ wsb)
{
    const int role = blockIdx.x >> 6;
    const int c    = blockIdx.x & 63;
    const int tid  = threadIdx.x, lane = tid & 63, wv = tid >> 6;
    const int l15  = lane & 15, quad = lane >> 4;
    const int fbase = wv * 16 + quad * 4;
    const int rbase = c * 16;

    __shared__ __align__(16) char smem[42880];
    // producer carve: wodeb [128][134] (34304 B) + zb [2][16][134] (8576 B)
    unsigned short (*wodeb)[134]    = reinterpret_cast<unsigned short (*)[134]>(smem);
    unsigned short (*zb)[16][134]   = reinterpret_cast<unsigned short (*)[16][134]>(smem + 34304);
    // GRU carve: zbuf [2][16][LDP] (8576 B) + hidbuf [16][72] (2304 B)
    unsigned short (*zbuf)[16][LDP] = reinterpret_cast<unsigned short (*)[16][LDP]>(smem);
    unsigned short (*hidbuf)[72]    = reinterpret_cast<unsigned short (*)[72]>(smem + 8576);

    unsigned short* yTraj  = (unsigned short*)(wsb);
    unsigned short* h1Traj = (unsigned short*)(wsb + 0x2000000);
    unsigned int*   yflag  = (unsigned int*)(wsb + 0x4000000);
    unsigned int*   h1flag = (unsigned int*)(wsb + 0x4010000);
#define YMAGIC(t)  (0x5E000000u + (unsigned)(t))
#define H1MAGIC(t) (0x6E000000u + (unsigned)(t))

    if (role == 0) {
        // ---- all 8 waves stage Wode f32 -> LDS bf16 ----
        {
            int r = tid >> 2, c0 = (tid & 3) * 32;
            const float* wrow = Wode + r * CTOT + c0;
#pragma unroll
            for (int u = 0; u < 32; u += 8) {
                float4 a = *(const float4*)(wrow + u);
                float4 b = *(const float4*)(wrow + u + 4);
                *(uint2*)&wodeb[r][c0 + u]     = pack4(a.x, a.y, a.z, a.w);
                *(uint2*)&wodeb[r][c0 + u + 4] = pack4(b.x, b.y, b.z, b.w);
            }
        }

        const int row = rbase + l15;
        float y[2][4], yn[2][4], bl[2][4];
        if (wv < 4) {
            // wave wv owns features [32wv, 32wv+32): tiles j = 2wv, 2wv+1
#pragma unroll
            for (int jj = 0; jj < 2; ++jj) {
                int j = wv * 2 + jj;
#pragma unroll
                for (int i = 0; i < 4; ++i) {
                    int f = j * 16 + quad * 4 + i;
                    y[jj][i] = (f < 32) ? yl[row * 32 + f] : yh[row * 96 + (f - 32)];
                }
                uint2 pk = pack4(y[jj][0], y[jj][1], y[jj][2], y[jj][3]);
                *(uint2*)&zb[0][l15][j * 16 + quad * 4] = pk;
                stg8(yTraj + ((size_t)row) * CTOT + j * 16 + quad * 4, pk);
                float4 bv = *(const float4*)(bode + j * 16 + quad * 4);
                bl[jj][0] = bv.x * TWO_LOG2E; bl[jj][1] = bv.y * TWO_LOG2E;
                bl[jj][2] = bv.z * TWO_LOG2E; bl[jj][3] = bv.w * TWO_LOG2E;
            }
        }
        __syncthreads();   // full drain: y0 stores + wodeb visible everywhere

        if (wv >= 4) {
            // parked waves: match the producer's barrier count exactly
            for (int b = 0; b < NBAR; ++b) __builtin_amdgcn_s_barrier();
            return;
        }

        if (tid == 0)
            __hip_atomic_store(&yflag[c * 128 + 0], YMAGIC(0),
                               __ATOMIC_RELAXED, __HIP_MEMORY_SCOPE_AGENT);

        // dt-folded Dormand-Prince coefficients
        const float dt = 1.0f / 95.0f;
        const float d10 = dt * 0.2f;
        const float d20 = dt * (3.f/40.f),  d21 = dt * (9.f/40.f);
        const float d30 = dt * (44.f/45.f), d31 = dt * (-56.f/15.f), d32 = dt * (32.f/9.f);
        const float d40 = dt * (19372.f/6561.f), d41 = dt * (-25360.f/2187.f),
                    d42 = dt * (64448.f/6561.f), d43 = dt * (-212.f/729.f);
        const float d50 = dt * (9017.f/3168.f), d51 = dt * (-355.f/33.f),
                    d52 = dt * (46732.f/5247.f), d53 = dt * (49.f/176.f),
                    d54 = dt * (-5103.f/18656.f);
        const float e0 = dt * (35.f/384.f), e2 = dt * (500.f/1113.f), e3 = dt * (125.f/192.f),
                    e4 = dt * (-2187.f/6784.f), e5 = dt * (11.f/84.f);

        float kr[4][2][4];   // k1..k4 in f32 registers (32 VGPR)
        int pz = 0;
#pragma unroll 1
        for (int t = 0; t < 95; ++t) {
#pragma unroll
            for (int s = 0; s < 6; ++s) {
                bf16x8_t zf[4];
#pragma unroll
                for (int kt = 0; kt < 4; ++kt)
                    zf[kt] = ldfrag(&zb[pz][l15][kt * 32 + quad * 8]);
                f32x4_t acc[2];
                acc[0] = (f32x4_t){0.f, 0.f, 0.f, 0.f};
                acc[1] = (f32x4_t){0.f, 0.f, 0.f, 0.f};
#pragma unroll
                for (int kt = 0; kt < 4; ++kt)
#pragma unroll
                    for (int jj = 0; jj < 2; ++jj)
                        acc[jj] = mfma16(
                            ldfrag(&wodeb[(wv * 2 + jj) * 16 + l15][kt * 32 + quad * 8]),
                            zf[kt], acc[jj]);
                float kf[2][4];
#pragma unroll
                for (int jj = 0; jj < 2; ++jj)
#pragma unroll
                    for (int i = 0; i < 4; ++i)
                        kf[jj][i] = tanhfast(acc[jj][i], bl[jj][i]);
                if (s < 4)
#pragma unroll
                    for (int jj = 0; jj < 2; ++jj)
#pragma unroll
                        for (int i = 0; i < 4; ++i) kr[s][jj][i] = kf[jj][i];
                // y accumulation (fresh f32 k's; k2 has zero weight)
#pragma unroll
                for (int jj = 0; jj < 2; ++jj)
#pragma unroll
                    for (int i = 0; i < 4; ++i) {
                        if (s == 0)      yn[jj][i] = fmaf(e0, kf[jj][i], y[jj][i]);
                        else if (s == 2) yn[jj][i] = fmaf(e2, kf[jj][i], yn[jj][i]);
                        else if (s == 3) yn[jj][i] = fmaf(e3, kf[jj][i], yn[jj][i]);
                        else if (s == 4) yn[jj][i] = fmaf(e4, kf[jj][i], yn[jj][i]);
                        else if (s == 5) y[jj][i]  = fmaf(e5, kf[jj][i], yn[jj][i]);
                    }
                // next z, all-f32 register combine
#pragma unroll
                for (int jj = 0; jj < 2; ++jj) {
                    float zv[4];
#pragma unroll
                    for (int i = 0; i < 4; ++i) {
                        float zvv;
                        if (s == 0)      zvv = fmaf(d10, kf[jj][i], y[jj][i]);
                        else if (s == 1) zvv = fmaf(d21, kf[jj][i],
                                                fmaf(d20, kr[0][jj][i], y[jj][i]));
                        else if (s == 2) zvv = fmaf(d32, kf[jj][i],
                                                fmaf(d31, kr[1][jj][i],
                                                fmaf(d30, kr[0][jj][i], y[jj][i])));
                        else if (s == 3) zvv = fmaf(d43, kf[jj][i],
                                                fmaf(d42, kr[2][jj][i],
                                                fmaf(d41, kr[1][jj][i],
                                                fmaf(d40, kr[0][jj][i], y[jj][i]))));
                        else if (s == 4) zvv = fmaf(d54, kf[jj][i],
                                                fmaf(d53, kr[3][jj][i],
                                                fmaf(d52, kr[2][jj][i],
                                                fmaf(d51, kr[1][jj][i],
                                                fmaf(d50, kr[0][jj][i], y[jj][i])))));
                        else             zvv = y[jj][i];   // s==5: z_next = y_{t+1}
                        zv[i] = zvv;
                    }
                    int j = wv * 2 + jj;
                    uint2 pk = pack4(zv[0], zv[1], zv[2], zv[3]);
                    *(uint2*)&zb[pz ^ 1][l15][j * 16 + quad * 4] = pk;
                    if (s == 5)
                        stg8(yTraj + ((size_t)(t + 1) * 1024 + row) * CTOT + j * 16 + quad * 4, pk);
                }
                if (s == 1)   // every producer wave drains its t-1 stores (old, free)
                    asm volatile("s_waitcnt vmcnt(0)" ::: "memory");
                LGKM_BAR();
                if (s == 1 && t > 0 && tid == 0)   // all waves drained at the barrier
                    __hip_atomic_store(&yflag[c * 128 + t], YMAGIC(t),
                                       __ATOMIC_RELAXED, __HIP_MEMORY_SCOPE_AGENT);
                pz ^= 1;
            }
        }
        asm volatile("s_waitcnt vmcnt(0)" ::: "memory");
        __builtin_amdgcn_s_barrier();   // barrier #571: all y95 stores drained
        if (tid == 0)
            __hip_atomic_store(&yflag[c * 128 + 95], YMAGIC(95),
                               __ATOMIC_RELAXED, __HIP_MEMORY_SCOPE_AGENT);
        return;
    }

    // ==================== GRU consumer roles ==================================
    const float* Wih = (role == 1) ? Wih0 : Wih1;
    const float* Whh = (role == 1) ? Whh0 : Whh1;
    const float* bih = (role == 1) ? bih0 : bih1;
    const float* bhh = (role == 1) ? bhh0 : bhh1;
    const unsigned short* src = (role == 1) ? yTraj : h1Traj;

    bf16x8_t wih[3][4], whh[3][4];
#pragma unroll
    for (int g = 0; g < 3; ++g)
#pragma unroll
        for (int kt = 0; kt < 4; ++kt) {
            wih[g][kt] = ldfragW(Wih + (size_t)(g * 128 + wv * 16 + l15) * CTOT + kt * 32 + quad * 8);
            whh[g][kt] = ldfragW(Whh + (size_t)(g * 128 + wv * 16 + l15) * CTOT + kt * 32 + quad * 8);
        }
    float br[4], bz[4], bin_[4], bhn[4];
    {
        float4 a0 = *(const float4*)(bih + 0 * 128 + fbase);
        float4 b0 = *(const float4*)(bhh + 0 * 128 + fbase);
        float4 a1 = *(const float4*)(bih + 1 * 128 + fbase);
        float4 b1 = *(const float4*)(bhh + 1 * 128 + fbase);
        float4 a2 = *(const float4*)(bih + 2 * 128 + fbase);
        float4 b2 = *(const float4*)(bhh + 2 * 128 + fbase);
        br[0] = a0.x + b0.x; br[1] = a0.y + b0.y; br[2] = a0.z + b0.z; br[3] = a0.w + b0.w;
        bz[0] = a1.x + b1.x; bz[1] = a1.y + b1.y; bz[2] = a1.z + b1.z; bz[3] = a1.w + b1.w;
        bin_[0] = a2.x; bin_[1] = a2.y; bin_[2] = a2.z; bin_[3] = a2.w;
        bhn[0] = b2.x; bhn[1] = b2.y; bhn[2] = b2.z; bhn[3] = b2.w;
    }

    float h[4] = {0.f, 0.f, 0.f, 0.f};
    *(uint2*)&zbuf[0][l15][fbase] = pack4(0.f, 0.f, 0.f, 0.f);
    int p = 0;
    __syncthreads();

    if (role == 1) {
#pragma unroll 1
        for (int t = 0; t < TPTS; ++t) {
            asm volatile("s_waitcnt vmcnt(0)" ::: "memory");   // drain t-1 h1 store (old, free)
            __builtin_amdgcn_s_barrier();                      // all waves drained
            if (tid == 0) {
                if (t > 0)
                    __hip_atomic_store(&h1flag[c * 128 + (t - 1)], H1MAGIC(t - 1),
                                       __ATOMIC_RELAXED, __HIP_MEMORY_SCOPE_AGENT);
                int guard = 0;
                while (__hip_atomic_load(&yflag[c * 128 + t],
                                         __ATOMIC_RELAXED, __HIP_MEMORY_SCOPE_AGENT) != YMAGIC(t)) {
                    __builtin_amdgcn_s_sleep(1);
                    if (++guard > (1 << 22)) break;
                }
            }
            __syncthreads();
            // issue x loads FIRST; their LLC latency hides under the gh MFMAs
            const unsigned short* xp = src + ((size_t)t * 1024 + rbase + l15) * CTOT;
            bf16x8_t ax[4];
#pragma unroll
            for (int kt = 0; kt < 4; ++kt) ax[kt] = ldfragG(xp + kt * 32 + quad * 8);
            bf16x8_t ah[4];
#pragma unroll
            for (int kt = 0; kt < 4; ++kt)
                ah[kt] = ldfrag(&zbuf[p][l15][kt * 32 + quad * 8]);
            f32x4_t gh[3], gx[3];
#pragma unroll
            for (int g = 0; g < 3; ++g) {
                gh[g] = (f32x4_t){0.f, 0.f, 0.f, 0.f};
                gx[g] = (f32x4_t){0.f, 0.f, 0.f, 0.f};
            }
#pragma unroll
            for (int kt = 0; kt < 4; ++kt) {
                gh[0] = mfma16(whh[0][kt], ah[kt], gh[0]);
                gh[1] = mfma16(whh[1][kt], ah[kt], gh[1]);
                gh[2] = mfma16(whh[2][kt], ah[kt], gh[2]);
            }
#pragma unroll
            for (int kt = 0; kt < 4; ++kt) {
                gx[0] = mfma16(wih[0][kt], ax[kt], gx[0]);
                gx[1] = mfma16(wih[1][kt], ax[kt], gx[1]);
                gx[2] = mfma16(wih[2][kt], ax[kt], gx[2]);
            }
#pragma unroll
            for (int i = 0; i < 4; ++i) {
                float rr = sigm(gx[0][i] + gh[0][i] + br[i]);
                float zz = sigm(gx[1][i] + gh[1][i] + bz[i]);
                float nn = tanh2((gx[2][i] + bin_[i]) + rr * (gh[2][i] + bhn[i]));
                h[i] = nn + zz * (h[i] - nn);
            }
            uint2 pk = pack4(h[0], h[1], h[2], h[3]);
            *(uint2*)&zbuf[p ^ 1][l15][fbase] = pk;
            stg8(h1Traj + ((size_t)t * 1024 + rbase + l15) * CTOT + fbase, pk);
            LGKM_BAR();          // LDS handoff only; h1 store drains next iter
            p ^= 1;
        }
        asm volatile("s_waitcnt vmcnt(0)" ::: "memory");
        __syncthreads();
        if (tid == 0)
            __hip_atomic_store(&h1flag[c * 128 + (TPTS - 1)], H1MAGIC(TPTS - 1),
                               __ATOMIC_RELAXED, __HIP_MEMORY_SCOPE_AGENT);
        return;
    }

    // role 2: GRU1 (no global stores in loop) + MLP head
#pragma unroll 1
    for (int t = 0; t < TPTS; ++t) {
        waitflag(&h1flag[c * 128 + t], H1MAGIC(t));
        const unsigned short* xp = src + ((size_t)t * 1024 + rbase + l15) * CTOT;
        bf16x8_t ax[4];
#pragma unroll
        for (int kt = 0; kt < 4; ++kt) ax[kt] = ldfragG(xp + kt * 32 + quad * 8);
        bf16x8_t ah[4];
#pragma unroll
        for (int kt = 0; kt < 4; ++kt)
            ah[kt] = ldfrag(&zbuf[p][l15][kt * 32 + quad * 8]);
        f32x4_t gh[3], gx[3];
#pragma unroll
        for (int g = 0; g < 3; ++g) {
            gh[g] = (f32x4_t){0.f, 0.f, 0.f, 0.f};
            gx[g] = (f32x4_t){0.f, 0.f, 0.f, 0.f};
        }
#pragma unroll
        for (int kt = 0; kt < 4; ++kt) {
            gh[0] = mfma16(whh[0][kt], ah[kt], gh[0]);
            gh[1] = mfma16(whh[1][kt], ah[kt], gh[1]);
            gh[2] = mfma16(whh[2][kt], ah[kt], gh[2]);
        }
#pragma unroll
        for (int kt = 0; kt < 4; ++kt) {
            gx[0] = mfma16(wih[0][kt], ax[kt], gx[0]);
            gx[1] = mfma16(wih[1][kt], ax[kt], gx[1]);
            gx[2] = mfma16(wih[2][kt], ax[kt], gx[2]);
        }
#pragma unroll
        for (int i = 0; i < 4; ++i) {
            float rr = sigm(gx[0][i] + gh[0][i] + br[i]);
            float zz = sigm(gx[1][i] + gh[1][i] + bz[i]);
            float nn = tanh2((gx[2][i] + bin_[i]) + rr * (gh[2][i] + bhn[i]));
            h[i] = nn + zz * (h[i] - nn);
        }
        *(uint2*)&zbuf[p ^ 1][l15][fbase] = pack4(h[0], h[1], h[2], h[3]);
        LGKM_BAR();
        p ^= 1;
    }

    // ==================== MLP head (role 2) ===================================
    if (wv < 4) {
        bf16x8_t wf[4], hf[4];
#pragma unroll
        for (int kt = 0; kt < 4; ++kt) {
            wf[kt] = ldfragW(W1v + (size_t)(wv * 16 + l15) * CTOT + kt * 32 + quad * 8);
            hf[kt] = ldfrag(&zbuf[p][l15][kt * 32 + quad * 8]);
        }
        f32x4_t acc = {0.f, 0.f, 0.f, 0.f};
#pragma unroll
        for (int kt = 0; kt < 4; ++kt) acc = mfma16(wf[kt], hf[kt], acc);
        float4 bb = *(const float4*)(b1v + wv * 16 + quad * 4);
        const float* bbp = (const float*)&bb;
        float gl[4];
#pragma unroll
        for (int i = 0; i < 4; ++i) {
            float x = acc[i] + bbp[i];
            gl[i] = 0.5f * x * (1.0f + erff(x * 0.70710678118654752f));
        }
        *(uint2*)&hidbuf[l15][wv * 16 + quad * 4] = pack4(gl[0], gl[1], gl[2], gl[3]);
    }
    __syncthreads();

    bf16x8_t ahid[2];
#pragma unroll
    for (int kt = 0; kt < 2; ++kt)
        ahid[kt] = ldfrag(&hidbuf[l15][kt * 32 + quad * 8]);
#pragma unroll 1
    for (int j = 0; j < 24; ++j) {
        int mt2 = wv * 24 + j;
        bf16x8_t wf0 = ldfragW(W2v + (size_t)(mt2 * 16 + l15) * 64 + quad * 8);
        bf16x8_t wf1 = ldfragW(W2v + (size_t)(mt2 * 16 + l15) * 64 + 32 + quad * 8);
        float4 bv = *(const float4*)(b2v + mt2 * 16 + quad * 4);
        const float* bvp = (const float*)&bv;
        f32x4_t acc = {0.f, 0.f, 0.f, 0.f};
        acc = mfma16(wf0, ahid[0], acc);
        acc = mfma16(wf1, ahid[1], acc);
        float4 o;
        o.x = acc[0] + bvp[0]; o.y = acc[1] + bvp[1];
        o.z = acc[2] + bvp[2]; o.w = acc[3] + bvp[3];
        *(float4*)(outp + (size_t)(rbase + l15) * 3072 + mt2 * 16 + quad * 4) = o;
    }
#undef YMAGIC
#undef H1MAGIC
}

extern "C" void kernel_launch(void* const* d_in, const int* in_sizes, int n_in,
                              void* d_out, int out_size, void* d_ws, size_t ws_size,
                              hipStream_t stream) {
    // setup_inputs order: 0:x(unused) 1:yl 2:yh 3:W_ode 4:b_ode 5:W_ih0 6:W_hh0
    // 7:b_ih0 8:b_hh0 9:W_ih1 10:W_hh1 11:b_ih1 12:b_hh1 13:W1 14:b1 15:W2 16:b2
    const float* yl   = (const float*)d_in[1];
    const float* yh   = (const float*)d_in[2];
    const float* Wode = (const float*)d_in[3];
    const float* bode = (const float*)d_in[4];
    const float* Wih0 = (const float*)d_in[5];
    const float* Whh0 = (const float*)d_in[6];
    const float* bih0 = (const float*)d_in[7];
    const float* bhh0 = (const float*)d_in[8];
    const float* Wih1 = (const float*)d_in[9];
    const float* Whh1 = (const float*)d_in[10];
    const float* bih1 = (const float*)d_in[11];
    const float* bhh1 = (const float*)d_in[12];
    const float* W1v  = (const float*)d_in[13];
    const float* b1v  = (const float*)d_in[14];
    const float* W2v  = (const float*)d_in[15];
    const float* b2v  = (const float*)d_in[16];

    ode_forecaster<<<dim3(192), dim3(512), 0, stream>>>(
        yl, yh, Wode, bode, Wih0, Whh0, bih0, bhh0,
        Wih1, Whh1, bih1, bhh1, W1v, b1v, W2v, b2v,
        (float*)d_out, (char*)d_ws);
}